// Round 9
// baseline (47.339 us; speedup 1.0000x reference)
//
#include <hip/hip_runtime.h>
#include <math.h>

#define BB 2
#define NN 512
#define NIN 64
#define NF 192
#define HH 128
#define NOUT 8

typedef short short8 __attribute__((ext_vector_type(8)));
typedef float f32x4 __attribute__((ext_vector_type(4)));

__device__ __forceinline__ float celu1(float x) {
    return x > 0.0f ? x : expm1f(x);
}

__device__ __forceinline__ ushort f2b(float f) {
    union { float f; uint u; } v; v.f = f;
    uint r = v.u + 0x7fffu + ((v.u >> 16) & 1u);   // RNE
    return (ushort)(r >> 16);
}
__device__ __forceinline__ uint pack2(float a, float b) {
    return (uint)f2b(a) | ((uint)f2b(b) << 16);
}
// load 8 consecutive f32, convert to a bf16 MFMA fragment in-register
__device__ __forceinline__ short8 cvt8(const float* __restrict__ p) {
    float4 a = *(const float4*)p;
    float4 b = *(const float4*)(p + 4);
    union { uint4 u; short8 s; } c;
    c.u.x = pack2(a.x, a.y); c.u.y = pack2(a.z, a.w);
    c.u.z = pack2(b.x, b.y); c.u.w = pack2(b.z, b.w);
    return c.s;
}

// t_s XOR swizzle (validated R6): byte = m*256 + (col*2 ^ (key(m)<<4)),
// key(m) = (m ^ (m>>3)) & 7.  Phase-1 ds_write_b64 (dm=8/lane) and phase-2
// ds_read_b128 (dm=1/lane) both land 2-way max (free).
__device__ __forceinline__ ushort* tsw(ushort* t_s, int m, int col) {
    int key = (m ^ (m >> 3)) & 7;
    int byte = m * 256 + ((col * 2) ^ (key << 4));
    return (ushort*)((char*)t_s + byte);
}

// ---------------------------------------------------------------------------
// Single launch, grid 256 x 512 threads (8 waves/block, 32 KB LDS, <=128 VGPR
// => capacity >= 2 blocks/CU => all 256 blocks co-resident: barrier is safe).
//
// Stage A:
//   blocks 0..7   : LDS-transpose+cvt Wb[o][h][g] -> Wt[o][g][h], o = bid
//                   (64x64 f32 tiles in scratch aliased onto t_s).
//   blocks 8..135 : fc wave-jobs fj = (bid-8)*8+wave in [0,1024):
//                   mb = fj&63 (m-tile 16), lr = (fj>>6)&1, ht = fj>>7 (16 h).
//                   Validated R4 fc body (pairing folded into B-frag address).
//   blocks 136+   : idle in stage A.
// Barrier: syncthreads; tid0: threadfence + atomicAdd(cnt); tid0 spins
//   (s_sleep(8) backoff) until cnt==256; threadfence; syncthreads.
// Stage B: validated R6 k2 body (swizzled t_s phase 1, register-B phase 2,
//   float4 epilogue).  bid -> j0=(bid&3)*128, i0=((bid>>2)&31)*16, b=bid>>7.
// ---------------------------------------------------------------------------
__global__ __launch_bounds__(512, 4) void fused_kernel(
    const float* __restrict__ x_l, const float* __restrict__ x_r,
    const float* __restrict__ Wl, const float* __restrict__ bl,
    const float* __restrict__ Wr, const float* __restrict__ br,
    const float* __restrict__ Wb, const float* __restrict__ bias_b,
    ushort* __restrict__ hl_bf, ushort* __restrict__ hr_bf,
    ushort* __restrict__ Wt, unsigned* __restrict__ cnt,
    float* __restrict__ out)
{
    __shared__ ushort t_s[128 * 128];   // 32 KiB; stage-A transpose scratch + stage-B t tile

    int bid = blockIdx.x;
    int tid = threadIdx.x;
    int wave = tid >> 6;
    int lane = tid & 63;
    int lrow = lane & 15;
    int lgrp = lane >> 4;

    // ================= stage A =================
    if (bid < 8) {
        // ---- Wb transpose for o = bid, via 64x64 f32 LDS tiles ----
        int o = bid;
        float* scr = (float*)t_s;            // 64*65 f32 = 16.6 KB < 32 KB
        #pragma unroll
        for (int h0 = 0; h0 < HH; h0 += 64) {
            #pragma unroll
            for (int g0 = 0; g0 < HH; g0 += 64) {
                for (int idx = tid; idx < 64 * 64; idx += 512) {
                    int hh = idx >> 6;       // 0..63
                    int g  = idx & 63;
                    scr[g * 65 + hh] = Wb[(o * HH + h0 + hh) * HH + g0 + g];
                }
                __syncthreads();
                for (int idx = tid; idx < 64 * 64; idx += 512) {
                    int g  = idx >> 6;       // 0..63
                    int hh = idx & 63;
                    Wt[(o * HH + g0 + g) * HH + h0 + hh] = f2b(scr[g * 65 + hh]);
                }
                __syncthreads();
            }
        }
    } else if (bid < 136) {
        // ---- fc wave-job ----
        int fj = (bid - 8) * 8 + wave;       // 0..1023
        int mb = fj & 63;
        int lr = (fj >> 6) & 1;
        int ht = fj >> 7;                    // 0..7
        int m0 = mb * 16;
        int b  = m0 >> 9;
        int i_base = m0 & (NN - 1);
        int h0 = ht * 16;
        int i = i_base + lrow;

        const float* Wm   = lr ? Wr : Wl;
        const float* bias = lr ? br : bl;
        const float* xa   = lr ? x_r : x_l;
        ushort* dst       = lr ? hr_bf : hl_bf;

        short8 bf[6];
        #pragma unroll
        for (int kk = 0; kk < 6; ++kk) {
            int part = kk >> 1;
            int c0 = (kk & 1) * 32 + lgrp * 8;
            int s; const float* src;
            if (part == 0)      { s = 0;            src = x_l; }
            else if (part == 1) { s = lr ? +1 : -1; src = xa; }
            else                { s = lr ? -1 : +1; src = xa; }
            int row = i + s;
            short8 v = (short8)0;
            if ((unsigned)row < (unsigned)NN)
                v = cvt8(&src[(b * NN + row) * NIN + c0]);
            bf[kk] = v;
        }

        f32x4 acc = (f32x4)(0.0f);
        #pragma unroll
        for (int kk = 0; kk < 6; ++kk) {
            short8 afrag = cvt8(&Wm[(h0 + lrow) * NF + kk * 32 + lgrp * 8]);
            acc = __builtin_amdgcn_mfma_f32_16x16x32_bf16(afrag, bf[kk], acc, 0, 0, 0);
        }

        int h_base = h0 + lgrp * 4;
        float4 bv = *(const float4*)&bias[h_base];
        int m = m0 + lrow;
        uint2 v;
        v.x = pack2(celu1(acc[0] + bv.x), celu1(acc[1] + bv.y));
        v.y = pack2(celu1(acc[2] + bv.z), celu1(acc[3] + bv.w));
        *(uint2*)&dst[m * HH + h_base] = v;
    }
    // blocks 136..255: no stage-A work

    // ================= device barrier =================
    __syncthreads();
    if (tid == 0) {
        __threadfence();                     // release: flush stage-A writes
        atomicAdd(cnt, 1u);
        while (atomicAdd(cnt, 0u) < 256u)    // coherent poll at L2-bypass point
            __builtin_amdgcn_s_sleep(8);
        __threadfence();                     // acquire: invalidate stale cache
    }
    __syncthreads();

    // ================= stage B (validated R6 body) =================
    int j0 = (bid & 3) * 128;
    int i0 = ((bid >> 2) & 31) * 16;
    int b  = bid >> 7;

    // ---- prefetch phase-2 B fragments (hr), one j-subtile per wave ----
    int jw = j0 + wave * 16;
    const ushort* hb = hr_bf + (size_t)b * NN * HH;
    short8 bfr[4];
    #pragma unroll
    for (int kk = 0; kk < 4; ++kk)
        bfr[kk] = *(const short8*)&hb[(jw + lrow) * HH + kk * 32 + lgrp * 8];

    // ---- phase 1: build t tile in swizzled LDS (wave w -> o = w) ----
    short8 hfrag[4];
    #pragma unroll
    for (int kk = 0; kk < 4; ++kk)
        hfrag[kk] = *(const short8*)&hl_bf[(b * NN + i0 + lrow) * HH + kk * 32 + lgrp * 8];

    int o_p1 = wave;
    #pragma unroll
    for (int gt = 0; gt < 8; ++gt) {
        int g_base = gt * 16;
        f32x4 acc = (f32x4)(0.0f);
        #pragma unroll
        for (int kk = 0; kk < 4; ++kk) {
            short8 afrag = *(const short8*)&Wt[(o_p1 * HH + g_base + lrow) * HH + kk * 32 + lgrp * 8];
            acc = __builtin_amdgcn_mfma_f32_16x16x32_bf16(afrag, hfrag[kk], acc, 0, 0, 0);
        }
        // lane: i = lrow (D col), g = g_base + lgrp*4 + r (D row)
        int m  = lrow * 8 + o_p1;
        int gg = g_base + lgrp * 4;
        uint2 v;
        v.x = pack2(acc[0], acc[1]);
        v.y = pack2(acc[2], acc[3]);
        *(uint2*)tsw(t_s, m, gg) = v;
    }
    __syncthreads();

    // ---- phase 2: A from LDS (swizzled), B already in registers ----
    f32x4 acc2[8];
    #pragma unroll
    for (int ms = 0; ms < 8; ++ms) acc2[ms] = (f32x4)(0.0f);

    #pragma unroll
    for (int kk = 0; kk < 4; ++kk) {
        int koff = kk * 32 + lgrp * 8;
        #pragma unroll
        for (int ms = 0; ms < 8; ++ms) {
            short8 afr = *(const short8*)tsw(t_s, ms * 16 + lrow, koff);
            acc2[ms] = __builtin_amdgcn_mfma_f32_16x16x32_bf16(afr, bfr[kk], acc2[ms], 0, 0, 0);
        }
    }

    // ---- epilogue: 4 consecutive D rows -> same i, o0..o0+3; float4 store ----
    float4 b0 = *(const float4*)&bias_b[0];
    float4 b1 = *(const float4*)&bias_b[4];
    int j = jw + lrow;

    #pragma unroll
    for (int ms = 0; ms < 8; ++ms) {
        int m_base = ms * 16 + lgrp * 4;       // multiple of 4
        int i  = i0 + (m_base >> 3);
        int o0 = m_base & 7;                   // 0 or 4
        float4 bv = o0 ? b1 : b0;
        float4 v;
        v.x = acc2[ms][0] + bv.x;
        v.y = acc2[ms][1] + bv.y;
        v.z = acc2[ms][2] + bv.z;
        v.w = acc2[ms][3] + bv.w;
        float* dst = out + ((size_t)((b * NN + i) * NN + j)) * NOUT + o0;
        *(float4*)dst = v;
    }
}

// ---------------------------------------------------------------------------
extern "C" void kernel_launch(void* const* d_in, const int* in_sizes, int n_in,
                              void* d_out, int out_size, void* d_ws, size_t ws_size,
                              hipStream_t stream) {
    const float* x_l  = (const float*)d_in[0];
    const float* x_r  = (const float*)d_in[1];
    const float* Wl   = (const float*)d_in[2];
    const float* bl   = (const float*)d_in[3];
    const float* Wr   = (const float*)d_in[4];
    const float* br   = (const float*)d_in[5];
    const float* Wb   = (const float*)d_in[6];
    const float* bb   = (const float*)d_in[7];
    float* out = (float*)d_out;

    ushort* hl_bf = (ushort*)d_ws;                   // B*N*H = 131072 ushort
    ushort* hr_bf = hl_bf + BB * NN * HH;            // 131072
    ushort* Wt    = hr_bf + BB * NN * HH;            // 131072
    unsigned* cnt = (unsigned*)(Wt + NOUT * HH * HH);

    hipMemsetAsync(cnt, 0, sizeof(unsigned), stream);
    fused_kernel<<<256, 512, 0, stream>>>(x_l, x_r, Wl, bl, Wr, br, Wb, bb,
                                          hl_bf, hr_bf, Wt, cnt, out);
}